// Round 1
// baseline (220.906 us; speedup 1.0000x reference)
//
#include <hip/hip_runtime.h>
#include <hip/hip_bf16.h>
#include <math.h>

// Problem constants (BN, N, FIN, FO, H) from the reference
#define BN_   4
#define NN_   2048
#define FIN_  128
#define FO_   64
#define H_    4
#define D_    256   // FO*H

typedef __attribute__((ext_vector_type(8))) short bf16x8;   // 8 bf16 = 4 VGPRs
typedef __attribute__((ext_vector_type(4))) float floatx4;  // MFMA C/D frag

#define LOG2E 1.4426950408889634f

#if __has_builtin(__builtin_amdgcn_exp2f)
#define EXP2(x) __builtin_amdgcn_exp2f(x)
#else
#define EXP2(x) exp2f(x)
#endif

__device__ __forceinline__ float bf2f(short u) {
    union { unsigned int i; float f; } v;
    v.i = ((unsigned int)(unsigned short)u) << 16;
    return v.f;
}
__device__ __forceinline__ short f2bf(float f) {
    union { float f; unsigned int u; } v; v.f = f;
    unsigned int r = v.u + 0x7fffu + ((v.u >> 16) & 1u);  // RNE
    return (short)(unsigned short)(r >> 16);
}

// pack two floats to two bf16 (RNE) in one dword; elem0 in low 16 bits
#if defined(__BF16_MANT_DIG__)
typedef __bf16 bfr2 __attribute__((ext_vector_type(2)));
__device__ __forceinline__ unsigned int pack_bf16(float a, float b) {
    union { bfr2 h; unsigned int u; } v;
    v.h = (bfr2){(__bf16)a, (__bf16)b};
    return v.u;
}
#else
__device__ __forceinline__ unsigned int pack_bf16(float a, float b) {
    return ((unsigned int)(unsigned short)f2bf(a)) |
           (((unsigned int)(unsigned short)f2bf(b)) << 16);
}
#endif

// load 8 consecutive fp32 and round to a bf16x8 MFMA fragment
__device__ __forceinline__ bf16x8 load8f(const float* __restrict__ p) {
    floatx4 a = *(const floatx4*)p;
    floatx4 b = *(const floatx4*)(p + 4);
    union { bf16x8 v; unsigned int u[4]; } r;
    r.u[0] = pack_bf16(a[0], a[1]);
    r.u[1] = pack_bf16(a[2], a[3]);
    r.u[2] = pack_bf16(b[0], b[1]);
    r.u[3] = pack_bf16(b[2], b[3]);
    return r.v;
}

// ---------------------------------------------------------------------------
// Kernel 1: PT[b_rel][h][f][j] = sum_c x[b,j,c] * W_proj[f*H+h, c]  (bf16)
// PT slab per batch: row index (b_rel*D_ + h*64 + f), j contiguous.
// MFMA 16x16x32 bf16: A[m=lane&15][k=quad*8+e]=W rows, B[n=lane&15][k]=x.
// ---------------------------------------------------------------------------
__global__ __launch_bounds__(256) void proj_kernel(
    const float* __restrict__ x,      // (BN, NN, FIN) fp32
    const float* __restrict__ wproj,  // (D, FIN) fp32
    short* __restrict__ pt,           // (nb*D, NN) bf16 slabs
    int b0)
{
    const int tid  = threadIdx.x;
    const int wave = tid >> 6;
    const int lane = tid & 63;
    const int l16  = lane & 15;
    const int quad = lane >> 4;

    const int b_rel = blockIdx.z;
    const int b  = b0 + b_rel;
    const int h  = blockIdx.y;            // D_/64 == H_, so y-block == head
    const int d0 = h * 64;
    const int j0 = blockIdx.x * 256 + wave * 64;

    floatx4 acc[4][4];
#pragma unroll
    for (int mi = 0; mi < 4; ++mi)
#pragma unroll
        for (int nj = 0; nj < 4; ++nj)
            acc[mi][nj] = (floatx4){0.f, 0.f, 0.f, 0.f};

#pragma unroll
    for (int kc = 0; kc < 4; ++kc) {
        const int c = kc * 32 + quad * 8;
        bf16x8 afr[4], bfr[4];
#pragma unroll
        for (int mi = 0; mi < 4; ++mi) {
            int f = (d0 + mi * 16 + l16) & 63;
            int srow = f * H_ + h;                // W_proj row (flat d = f*H+h)
            afr[mi] = load8f(wproj + srow * FIN_ + c);
        }
#pragma unroll
        for (int nj = 0; nj < 4; ++nj) {
            int j = j0 + nj * 16 + l16;
            bfr[nj] = load8f(x + ((size_t)b * NN_ + j) * FIN_ + c);
        }
#pragma unroll
        for (int mi = 0; mi < 4; ++mi)
#pragma unroll
            for (int nj = 0; nj < 4; ++nj)
                acc[mi][nj] = __builtin_amdgcn_mfma_f32_16x16x32_bf16(
                    afr[mi], bfr[nj], acc[mi][nj], 0, 0, 0);
    }

    // C/D layout: col(n=j) = lane&15, row(m=d') = quad*4 + reg
#pragma unroll
    for (int mi = 0; mi < 4; ++mi) {
#pragma unroll
        for (int r = 0; r < 4; ++r) {
            int dp = d0 + mi * 16 + quad * 4 + r;
            size_t base = ((size_t)b_rel * D_ + dp) * NN_;
#pragma unroll
            for (int nj = 0; nj < 4; ++nj) {
                int j = j0 + nj * 16 + l16;
                pt[base + j] = f2bf(acc[mi][nj][r]);
            }
        }
    }
}

// ---------------------------------------------------------------------------
// Kernel 2: fused attention, I-tile = 32 (was 64). Block = 8 waves on the
// SAME (b, head, 32-row i-tile); waves split j (256 each). Each wave holds
// 2 16-row A-fragments sharing the same pt B-fragments (2x reuse).
//
// Round-8 change: counters showed latency-bound (Occupancy 20.6% = 1
// block/CU from a 256-block grid; VALUBusy 27%, MfmaUtil 3%, HBM 7.5%).
// IT 64->32 doubles the grid to 512 blocks -> 2 blocks/CU = 16 waves/CU
// (4 waves/SIMD). acc[2][4] (32 VGPRs) makes the 128-VGPR cap of
// __launch_bounds__(512,4) safe (round-7 spill was acc[4][4] at this cap)
// and leaves headroom for deeper load prefetch by the scheduler.
// ---------------------------------------------------------------------------
#define RSTRIDE 65   // LDS row stride (pad +1 col to break bank alignment)
#define WSLOT   (RSTRIDE * 16 + 16)   // 1056 floats per wave slot

__global__ __launch_bounds__(512, 4) void attn_kernel(
    const float* __restrict__ adj,    // (BN, NN, NN) fp32
    const short* __restrict__ pt,     // (nb*D, NN) bf16
    const float* __restrict__ ssrc,   // (H, FO) fp32
    const float* __restrict__ stgt,   // (H, FO) fp32
    const float* __restrict__ bias,   // (D,) fp32
    float* __restrict__ out,          // (BN, NN, D) fp32
    int b0)
{
    __shared__ float red[8][WSLOT];   // 33792 B (reduction scratch)
    __shared__ float st_lds[8][256];  // per-wave s_tgt slice (8 KiB)
    __shared__ float ss_lds[32];      // s_src for the i-tile

    const int tid  = threadIdx.x;
    const int w    = tid >> 6;        // wave = j-slice
    const int lane = tid & 63;
    const int l16  = lane & 15;
    const int quad = lane >> 4;

    const int b_rel = blockIdx.z;
    const int b  = b0 + b_rel;
    const int h  = blockIdx.y;
    const int i0 = blockIdx.x * 32;

    const short* pt_bh = pt + ((size_t)b_rel * D_ + h * FO_) * NN_;

    // my 4 f-rows' score weights (f = K*16 + l16)
    float stw[4], ssw[4];
#pragma unroll
    for (int K = 0; K < 4; ++K) {
        stw[K] = stgt[h * FO_ + K * 16 + l16];
        ssw[K] = ssrc[h * FO_ + K * 16 + l16];
    }

    // ---- preamble A: s_tgt for this wave's 256-j slice -> st_lds[w] ----
#pragma unroll
    for (int pj = 0; pj < 8; ++pj) {
        const int c = w * 256 + pj * 32 + quad * 8;
        bf16x8 p0 = *(const bf16x8*)(pt_bh + (size_t)(l16) * NN_ + c);
        bf16x8 p1 = *(const bf16x8*)(pt_bh + (size_t)(16 + l16) * NN_ + c);
        bf16x8 p2 = *(const bf16x8*)(pt_bh + (size_t)(32 + l16) * NN_ + c);
        bf16x8 p3 = *(const bf16x8*)(pt_bh + (size_t)(48 + l16) * NN_ + c);
#pragma unroll
        for (int e = 0; e < 8; ++e) {
            float t = stw[0] * bf2f(p0[e]) + stw[1] * bf2f(p1[e])
                    + stw[2] * bf2f(p2[e]) + stw[3] * bf2f(p3[e]);
            t += __shfl_xor(t, 1, 64); t += __shfl_xor(t, 2, 64);
            t += __shfl_xor(t, 4, 64); t += __shfl_xor(t, 8, 64);
            if (l16 == 0) st_lds[w][pj * 32 + quad * 8 + e] = t;
        }
    }

    // ---- preamble B: s_src for the 32 i-rows (wave 0) -> ss_lds ----
    if (w == 0) {
        const int c = i0 + quad * 8;
        bf16x8 p0 = *(const bf16x8*)(pt_bh + (size_t)(l16) * NN_ + c);
        bf16x8 p1 = *(const bf16x8*)(pt_bh + (size_t)(16 + l16) * NN_ + c);
        bf16x8 p2 = *(const bf16x8*)(pt_bh + (size_t)(32 + l16) * NN_ + c);
        bf16x8 p3 = *(const bf16x8*)(pt_bh + (size_t)(48 + l16) * NN_ + c);
#pragma unroll
        for (int e = 0; e < 8; ++e) {
            float t = ssw[0] * bf2f(p0[e]) + ssw[1] * bf2f(p1[e])
                    + ssw[2] * bf2f(p2[e]) + ssw[3] * bf2f(p3[e]);
            t += __shfl_xor(t, 1, 64); t += __shfl_xor(t, 2, 64);
            t += __shfl_xor(t, 4, 64); t += __shfl_xor(t, 8, 64);
            if (l16 == 0) ss_lds[quad * 8 + e] = t;
        }
    }
    __syncthreads();

    // per-lane s_src for my 2 sub-tiles (row = sub*16 + l16)
    float ssv[2];
#pragma unroll
    for (int sub = 0; sub < 2; ++sub)
        ssv[sub] = ss_lds[sub * 16 + l16];

    // pre-offset global bases (wave j-slice + quad offset folded in)
    const int qo = quad * 8;
    const float* adj_s[2];
#pragma unroll
    for (int sub = 0; sub < 2; ++sub)
        adj_s[sub] = adj + ((size_t)b * NN_ + i0 + sub * 16 + l16) * NN_ + w * 256 + qo;
    const short* ptr_f[4];
#pragma unroll
    for (int K = 0; K < 4; ++K)
        ptr_f[K] = pt_bh + (size_t)(K * 16 + l16) * NN_ + w * 256 + qo;
    const float* stp = &st_lds[w][qo];

    floatx4 acc[2][4];                // [i-sub][f-block], 32 regs
#pragma unroll
    for (int sub = 0; sub < 2; ++sub)
#pragma unroll
        for (int K = 0; K < 4; ++K)
            acc[sub][K] = (floatx4){0.f, 0.f, 0.f, 0.f};
    float ls[2] = {0.f, 0.f};

#pragma unroll
    for (int jt = 0; jt < 8; ++jt) {              // 8 iters x 32 j per wave
        const int o = jt * 32;                    // static element offset
        floatx4 stA = *(const floatx4*)(stp + o);
        floatx4 stB = *(const floatx4*)(stp + o + 4);
        bf16x8 bf[4];
#pragma unroll
        for (int K = 0; K < 4; ++K)
            bf[K] = *(const bf16x8*)(ptr_f[K] + o);
        // hoist BOTH subs' adj loads ahead of the exp/MFMA chain
        floatx4 ajA[2], ajB[2];
#pragma unroll
        for (int sub = 0; sub < 2; ++sub) {
            ajA[sub] = *(const floatx4*)(adj_s[sub] + o);
            ajB[sub] = *(const floatx4*)(adj_s[sub] + o + 4);
        }

#pragma unroll
        for (int sub = 0; sub < 2; ++sub) {
            union { bf16x8 v; unsigned int u[4]; } a0;
            float wv[8];
#pragma unroll
            for (int e = 0; e < 8; ++e) {
                float stv = (e < 4) ? stA[e] : stB[e - 4];
                float av  = (e < 4) ? ajA[sub][e] : ajB[sub][e - 4];
                float s = ssv[sub] + stv;
                s = fmaxf(s, 0.2f * s);           // leaky_relu(0.2)
                float u = (s + av) * LOG2E;
                wv[e] = EXP2(u);
            }
            // tree-sum the denominator (shorter serial chain than 8 adds)
            float s01 = wv[0] + wv[1], s23 = wv[2] + wv[3];
            float s45 = wv[4] + wv[5], s67 = wv[6] + wv[7];
            ls[sub] += (s01 + s23) + (s45 + s67);
            a0.u[0] = pack_bf16(wv[0], wv[1]);
            a0.u[1] = pack_bf16(wv[2], wv[3]);
            a0.u[2] = pack_bf16(wv[4], wv[5]);
            a0.u[3] = pack_bf16(wv[6], wv[7]);
#pragma unroll
            for (int K = 0; K < 4; ++K)
                acc[sub][K] = __builtin_amdgcn_mfma_f32_16x16x32_bf16(
                    a0.v, bf[K], acc[sub][K], 0, 0, 0);
        }
    }

    // wave-local row-sums over quads (row = sub*16 + l16 in A-layout)
#pragma unroll
    for (int sub = 0; sub < 2; ++sub) {
        ls[sub] += __shfl_xor(ls[sub], 16, 64);
        ls[sub] += __shfl_xor(ls[sub], 32, 64);
    }

    // epilogue: 2 chunks of 16 rows; 8-wave LDS reduction per chunk
#pragma unroll
    for (int sub = 0; sub < 2; ++sub) {
        __syncthreads();   // protect red[] from previous chunk's readers
#pragma unroll
        for (int K = 0; K < 4; ++K)
#pragma unroll
            for (int r = 0; r < 4; ++r)
                red[w][(quad * 4 + r) * RSTRIDE + K * 16 + l16] = acc[sub][K][r];
        if (quad == 0)
            red[w][16 * RSTRIDE + l16] = ls[sub];
        __syncthreads();
#pragma unroll
        for (int p = 0; p < 2; ++p) {
            int e   = tid + p * 512;
            int row = e >> 6;
            int col = e & 63;
            float s = 0.f, l = 0.f;
#pragma unroll
            for (int ww = 0; ww < 8; ++ww) {
                s += red[ww][row * RSTRIDE + col];
                l += red[ww][16 * RSTRIDE + row];
            }
            float v = s / l + bias[h * FO_ + col];
            v = (v > 0.f) ? v : expm1f(v);        // elu (fp32 out)
            out[((size_t)b * NN_ + i0 + sub * 16 + row) * D_ + h * FO_ + col] = v;
        }
    }
}

// ---------------------------------------------------------------------------
extern "C" void kernel_launch(void* const* d_in, const int* in_sizes, int n_in,
                              void* d_out, int out_size, void* d_ws, size_t ws_size,
                              hipStream_t stream) {
    const float* x     = (const float*)d_in[0];   // (4,2048,128) fp32
    const float* adj   = (const float*)d_in[1];   // (4,2048,2048) fp32
    const float* wproj = (const float*)d_in[2];   // (256,128) fp32
    const float* ssrc  = (const float*)d_in[3];   // (4,64) fp32
    const float* stgt  = (const float*)d_in[4];   // (4,64) fp32
    const float* bias  = (const float*)d_in[5];   // (256,) fp32
    float* out = (float*)d_out;                   // (4,2048,256) fp32

    // ws layout: PT slabs only (1 MiB per batch)
    const size_t SLAB = (size_t)D_ * NN_ * 2;
    short* pt = (short*)d_ws;

    int nb = (int)(ws_size / SLAB);
    if (nb < 1) nb = 1;
    if (nb > 4) nb = 4;

    for (int bb0 = 0; bb0 < BN_; bb0 += nb) {
        int cnt = (BN_ - bb0 < nb) ? (BN_ - bb0) : nb;
        proj_kernel<<<dim3(NN_ / 256, H_, cnt), 256, 0, stream>>>(
            x, wproj, pt, bb0);
        attn_kernel<<<dim3(NN_ / 32, H_, cnt), 512, 0, stream>>>(
            adj, pt, ssrc, stgt, bias, out, bb0);
    }
}

// Round 2
// 193.532 us; speedup vs baseline: 1.1414x; 1.1414x over previous
//
#include <hip/hip_runtime.h>
#include <hip/hip_bf16.h>
#include <math.h>

// Problem constants (BN, N, FIN, FO, H) from the reference
#define BN_   4
#define NN_   2048
#define FIN_  128
#define FO_   64
#define H_    4
#define D_    256   // FO*H

typedef __attribute__((ext_vector_type(8))) short bf16x8;   // 8 bf16 = 4 VGPRs
typedef __attribute__((ext_vector_type(4))) float floatx4;  // MFMA C/D frag

#define LOG2E 1.4426950408889634f

#if __has_builtin(__builtin_amdgcn_exp2f)
#define EXP2(x) __builtin_amdgcn_exp2f(x)
#else
#define EXP2(x) exp2f(x)
#endif

__device__ __forceinline__ float bf2f(short u) {
    union { unsigned int i; float f; } v;
    v.i = ((unsigned int)(unsigned short)u) << 16;
    return v.f;
}
__device__ __forceinline__ short f2bf(float f) {
    union { float f; unsigned int u; } v; v.f = f;
    unsigned int r = v.u + 0x7fffu + ((v.u >> 16) & 1u);  // RNE
    return (short)(unsigned short)(r >> 16);
}

// pack two floats to two bf16 (RNE) in one dword; elem0 in low 16 bits
#if defined(__BF16_MANT_DIG__)
typedef __bf16 bfr2 __attribute__((ext_vector_type(2)));
__device__ __forceinline__ unsigned int pack_bf16(float a, float b) {
    union { bfr2 h; unsigned int u; } v;
    v.h = (bfr2){(__bf16)a, (__bf16)b};
    return v.u;
}
#else
__device__ __forceinline__ unsigned int pack_bf16(float a, float b) {
    return ((unsigned int)(unsigned short)f2bf(a)) |
           (((unsigned int)(unsigned short)f2bf(b)) << 16);
}
#endif

// load 8 consecutive fp32 and round to a bf16x8 MFMA fragment
__device__ __forceinline__ bf16x8 load8f(const float* __restrict__ p) {
    floatx4 a = *(const floatx4*)p;
    floatx4 b = *(const floatx4*)(p + 4);
    union { bf16x8 v; unsigned int u[4]; } r;
    r.u[0] = pack_bf16(a[0], a[1]);
    r.u[1] = pack_bf16(a[2], a[3]);
    r.u[2] = pack_bf16(b[0], b[1]);
    r.u[3] = pack_bf16(b[2], b[3]);
    return r.v;
}

// ---------------------------------------------------------------------------
// Kernel 1: PT[b_rel][h][f][j] = sum_c x[b,j,c] * W_proj[f*H+h, c]  (bf16)
// PLUS: s_src[b_rel][h][j], s_tgt[b_rel][h][j] computed from the fp32
// accumulators (score dot over f) and stored to workspace. This deletes the
// attn kernel's preambles, which round-1 showed were recomputed 64x-128x
// redundantly (once per i-tile block).
// ---------------------------------------------------------------------------
__global__ __launch_bounds__(256) void proj_kernel(
    const float* __restrict__ x,      // (BN, NN, FIN) fp32
    const float* __restrict__ wproj,  // (D, FIN) fp32
    const float* __restrict__ ssrc,   // (H, FO) fp32
    const float* __restrict__ stgt,   // (H, FO) fp32
    short* __restrict__ pt,           // (nb*D, NN) bf16 slabs
    float* __restrict__ sS,           // (nb*H, NN) fp32
    float* __restrict__ sT,           // (nb*H, NN) fp32
    int b0)
{
    const int tid  = threadIdx.x;
    const int wave = tid >> 6;
    const int lane = tid & 63;
    const int l16  = lane & 15;
    const int quad = lane >> 4;

    const int b_rel = blockIdx.z;
    const int b  = b0 + b_rel;
    const int h  = blockIdx.y;            // D_/64 == H_, so y-block == head
    const int d0 = h * 64;
    const int j0 = blockIdx.x * 256 + wave * 64;

    floatx4 acc[4][4];
#pragma unroll
    for (int mi = 0; mi < 4; ++mi)
#pragma unroll
        for (int nj = 0; nj < 4; ++nj)
            acc[mi][nj] = (floatx4){0.f, 0.f, 0.f, 0.f};

#pragma unroll
    for (int kc = 0; kc < 4; ++kc) {
        const int c = kc * 32 + quad * 8;
        bf16x8 afr[4], bfr[4];
#pragma unroll
        for (int mi = 0; mi < 4; ++mi) {
            int f = (d0 + mi * 16 + l16) & 63;
            int srow = f * H_ + h;                // W_proj row (flat d = f*H+h)
            afr[mi] = load8f(wproj + srow * FIN_ + c);
        }
#pragma unroll
        for (int nj = 0; nj < 4; ++nj) {
            int j = j0 + nj * 16 + l16;
            bfr[nj] = load8f(x + ((size_t)b * NN_ + j) * FIN_ + c);
        }
#pragma unroll
        for (int mi = 0; mi < 4; ++mi)
#pragma unroll
            for (int nj = 0; nj < 4; ++nj)
                acc[mi][nj] = __builtin_amdgcn_mfma_f32_16x16x32_bf16(
                    afr[mi], bfr[nj], acc[mi][nj], 0, 0, 0);
    }

    // C/D layout: col(n=j) = lane&15, row(m=f within head) = mi*16+quad*4+r
#pragma unroll
    for (int mi = 0; mi < 4; ++mi) {
#pragma unroll
        for (int r = 0; r < 4; ++r) {
            int dp = d0 + mi * 16 + quad * 4 + r;
            size_t base = ((size_t)b_rel * D_ + dp) * NN_;
#pragma unroll
            for (int nj = 0; nj < 4; ++nj) {
                int j = j0 + nj * 16 + l16;
                pt[base + j] = f2bf(acc[mi][nj][r]);
            }
        }
    }

    // ---- score dot-products from fp32 accumulators ----
    // lane holds f = mi*16 + quad*4 + r for column j = j0 + nj*16 + l16
    float wsv[4][4], wtv[4][4];
#pragma unroll
    for (int mi = 0; mi < 4; ++mi)
#pragma unroll
        for (int r = 0; r < 4; ++r) {
            int f = mi * 16 + quad * 4 + r;
            wsv[mi][r] = ssrc[h * FO_ + f];
            wtv[mi][r] = stgt[h * FO_ + f];
        }
    const size_t sbase = ((size_t)b_rel * H_ + h) * NN_;
#pragma unroll
    for (int nj = 0; nj < 4; ++nj) {
        float ps = 0.f, pg = 0.f;
#pragma unroll
        for (int mi = 0; mi < 4; ++mi)
#pragma unroll
            for (int r = 0; r < 4; ++r) {
                ps = fmaf(wsv[mi][r], acc[mi][nj][r], ps);
                pg = fmaf(wtv[mi][r], acc[mi][nj][r], pg);
            }
        // sum the 4 quads (each holds 16 of the 64 f's)
        ps += __shfl_xor(ps, 16, 64); ps += __shfl_xor(ps, 32, 64);
        pg += __shfl_xor(pg, 16, 64); pg += __shfl_xor(pg, 32, 64);
        if (quad == 0) {
            int j = j0 + nj * 16 + l16;
            sS[sbase + j] = ps;
            sT[sbase + j] = pg;
        }
    }
}

// ---------------------------------------------------------------------------
// Kernel 2: fused attention, ALL 4 HEADS per block, i-tile = 16.
// Round-2 theory: round-1 falsified wave starvation (occupancy 2x, dur worse)
// -> latency-bound on the adj->exp->MFMA chain. Head fusion makes each adj
// 16B load feed 4 heads (32 exps + 16 MFMA instead of 8+4), cuts adj logical
// reads 4x, and the precomputed s arrays delete both preambles.
// Grid = 128 i-tiles x 4 b = 512 blocks -> 2 blocks/CU, 4 waves/SIMD.
// acc[4h][4K] = 64 VGPRs; ~180 live at (512,2)'s 256 cap -> no spill.
// ---------------------------------------------------------------------------
#define RSTRIDE 65   // LDS row stride (pad +1 col to break bank alignment)
#define WSLOT   (RSTRIDE * 16 + 16)   // 1056 floats per wave slot

__global__ __launch_bounds__(512, 2) void attn_kernel(
    const float* __restrict__ adj,    // (BN, NN, NN) fp32
    const short* __restrict__ pt,     // (nb*D, NN) bf16
    const float* __restrict__ sS,     // (nb*H, NN) fp32
    const float* __restrict__ sT,     // (nb*H, NN) fp32
    const float* __restrict__ bias,   // (D,) fp32
    float* __restrict__ out,          // (BN, NN, D) fp32
    int b0)
{
    // st (main loop) and red (epilogue) never live simultaneously; the
    // h=0 epilogue __syncthreads separates all st reads from red writes.
    __shared__ union {
        float st[8][4][256];          // per-wave s_tgt slices, 4 heads (32 KiB)
        float red[8][WSLOT];          // cross-wave reduction scratch (33 KiB)
    } sm;

    const int tid  = threadIdx.x;
    const int w    = tid >> 6;        // wave = 256-wide j-slice
    const int lane = tid & 63;
    const int l16  = lane & 15;
    const int quad = lane >> 4;

    const int b_rel = blockIdx.z;
    const int b  = b0 + b_rel;
    const int i0 = blockIdx.x * 16;

    const short* pt_b = pt + (size_t)b_rel * D_ * NN_;
    const size_t sb = (size_t)b_rel * H_ * NN_;

    // stage s_tgt slices for all 4 heads (wave-private; no barrier needed)
    {
        const int t = lane * 4;
#pragma unroll
        for (int h = 0; h < 4; ++h)
            *(floatx4*)&sm.st[w][h][t] =
                *(const floatx4*)&sT[sb + (size_t)h * NN_ + w * 256 + t];
    }

    // per-lane s_src for my i-row (row = l16), all heads
    float ssv[4];
#pragma unroll
    for (int h = 0; h < 4; ++h)
        ssv[h] = sS[sb + (size_t)h * NN_ + i0 + l16];

    // pre-offset global bases (j-slice + quad offset folded in)
    const int qo = quad * 8;
    const float* adj_p = adj + ((size_t)b * NN_ + i0 + l16) * NN_ + w * 256 + qo;
    const short* ptr_hk[4][4];
#pragma unroll
    for (int h = 0; h < 4; ++h)
#pragma unroll
        for (int K = 0; K < 4; ++K)
            ptr_hk[h][K] = pt_b + (size_t)(h * FO_ + K * 16 + l16) * NN_ + w * 256 + qo;

    floatx4 acc[4][4];                // [head][f-block], 64 regs
#pragma unroll
    for (int h = 0; h < 4; ++h)
#pragma unroll
        for (int K = 0; K < 4; ++K)
            acc[h][K] = (floatx4){0.f, 0.f, 0.f, 0.f};
    float ls[4] = {0.f, 0.f, 0.f, 0.f};

#pragma unroll
    for (int jt = 0; jt < 8; ++jt) {              // 8 iters x 32 j per wave
        const int o = jt * 32;                    // static element offset
        // one adj load pair feeds all 4 heads
        floatx4 ajA = *(const floatx4*)(adj_p + o);
        floatx4 ajB = *(const floatx4*)(adj_p + o + 4);

#pragma unroll
        for (int h = 0; h < 4; ++h) {
            const float* stp = &sm.st[w][h][qo];
            floatx4 stA = *(const floatx4*)(stp + o);
            floatx4 stB = *(const floatx4*)(stp + o + 4);
            bf16x8 bfr[4];
#pragma unroll
            for (int K = 0; K < 4; ++K)
                bfr[K] = *(const bf16x8*)(ptr_hk[h][K] + o);

            auto sc = [&](float stv, float av) {
                float s = ssv[h] + stv;
                s = fmaxf(s, 0.2f * s);           // leaky_relu(0.2)
                return EXP2((s + av) * LOG2E);
            };
            float w0 = sc(stA[0], ajA[0]), w1 = sc(stA[1], ajA[1]);
            float w2 = sc(stA[2], ajA[2]), w3 = sc(stA[3], ajA[3]);
            float w4 = sc(stB[0], ajB[0]), w5 = sc(stB[1], ajB[1]);
            float w6 = sc(stB[2], ajB[2]), w7 = sc(stB[3], ajB[7 - 7 + 3]);
            ls[h] += ((w0 + w1) + (w2 + w3)) + ((w4 + w5) + (w6 + w7));
            union { bf16x8 v; unsigned int u[4]; } a0;
            a0.u[0] = pack_bf16(w0, w1);
            a0.u[1] = pack_bf16(w2, w3);
            a0.u[2] = pack_bf16(w4, w5);
            a0.u[3] = pack_bf16(w6, w7);
#pragma unroll
            for (int K = 0; K < 4; ++K)
                acc[h][K] = __builtin_amdgcn_mfma_f32_16x16x32_bf16(
                    a0.v, bfr[K], acc[h][K], 0, 0, 0);
        }
    }

    // wave-local row-sums over quads (row = l16 in A-layout)
#pragma unroll
    for (int h = 0; h < 4; ++h) {
        ls[h] += __shfl_xor(ls[h], 16, 64);
        ls[h] += __shfl_xor(ls[h], 32, 64);
    }

    // epilogue: 4 head-chunks of 16 rows; 8-wave LDS reduction per chunk
#pragma unroll
    for (int h = 0; h < 4; ++h) {
        __syncthreads();   // h=0: all st reads done; h>0: prev chunk read done
#pragma unroll
        for (int K = 0; K < 4; ++K)
#pragma unroll
            for (int r = 0; r < 4; ++r)
                sm.red[w][(quad * 4 + r) * RSTRIDE + K * 16 + l16] = acc[h][K][r];
        if (quad == 0)
            sm.red[w][16 * RSTRIDE + l16] = ls[h];
        __syncthreads();
#pragma unroll
        for (int p = 0; p < 2; ++p) {
            int e   = tid + p * 512;
            int row = e >> 6;
            int col = e & 63;
            float s = 0.f, l = 0.f;
#pragma unroll
            for (int ww = 0; ww < 8; ++ww) {
                s += sm.red[ww][row * RSTRIDE + col];
                l += sm.red[ww][16 * RSTRIDE + row];
            }
            float v = s / l + bias[h * FO_ + col];
            v = (v > 0.f) ? v : expm1f(v);        // elu (fp32 out)
            out[((size_t)b * NN_ + i0 + row) * D_ + h * FO_ + col] = v;
        }
    }
}

// ---------------------------------------------------------------------------
extern "C" void kernel_launch(void* const* d_in, const int* in_sizes, int n_in,
                              void* d_out, int out_size, void* d_ws, size_t ws_size,
                              hipStream_t stream) {
    const float* x     = (const float*)d_in[0];   // (4,2048,128) fp32
    const float* adj   = (const float*)d_in[1];   // (4,2048,2048) fp32
    const float* wproj = (const float*)d_in[2];   // (256,128) fp32
    const float* ssrc  = (const float*)d_in[3];   // (4,64) fp32
    const float* stgt  = (const float*)d_in[4];   // (4,64) fp32
    const float* bias  = (const float*)d_in[5];   // (256,) fp32
    float* out = (float*)d_out;                   // (4,2048,256) fp32

    // ws layout per batch: PT slab (1 MiB) + s_src/s_tgt (64 KiB)
    const size_t SLAB  = (size_t)D_ * NN_ * 2;          // bf16 PT
    const size_t SSLAB = (size_t)2 * H_ * NN_ * 4;      // fp32 sS+sT
    int nb = (int)(ws_size / (SLAB + SSLAB));
    if (nb < 1) nb = 1;
    if (nb > 4) nb = 4;

    short* pt = (short*)d_ws;
    float* sv = (float*)((char*)d_ws + (size_t)nb * SLAB);
    float* sS = sv;
    float* sT = sv + (size_t)nb * H_ * NN_;

    for (int bb0 = 0; bb0 < BN_; bb0 += nb) {
        int cnt = (BN_ - bb0 < nb) ? (BN_ - bb0) : nb;
        proj_kernel<<<dim3(NN_ / 256, H_, cnt), 256, 0, stream>>>(
            x, wproj, ssrc, stgt, pt, sS, sT, bb0);
        attn_kernel<<<dim3(NN_ / 16, 1, cnt), 512, 0, stream>>>(
            adj, pt, sS, sT, bias, out, bb0);
    }
}

// Round 4
// 192.981 us; speedup vs baseline: 1.1447x; 1.0029x over previous
//
#include <hip/hip_runtime.h>
#include <hip/hip_bf16.h>
#include <math.h>

// Problem constants (BN, N, FIN, FO, H) from the reference
#define BN_   4
#define NN_   2048
#define FIN_  128
#define FO_   64
#define H_    4
#define D_    256   // FO*H

typedef __attribute__((ext_vector_type(8))) short bf16x8;   // 8 bf16 = 4 VGPRs
typedef __attribute__((ext_vector_type(4))) float floatx4;  // MFMA C/D frag

#define LOG2E 1.4426950408889634f

#if __has_builtin(__builtin_amdgcn_exp2f)
#define EXP2(x) __builtin_amdgcn_exp2f(x)
#else
#define EXP2(x) exp2f(x)
#endif

__device__ __forceinline__ float bf2f(short u) {
    union { unsigned int i; float f; } v;
    v.i = ((unsigned int)(unsigned short)u) << 16;
    return v.f;
}
__device__ __forceinline__ short f2bf(float f) {
    union { float f; unsigned int u; } v; v.f = f;
    unsigned int r = v.u + 0x7fffu + ((v.u >> 16) & 1u);  // RNE
    return (short)(unsigned short)(r >> 16);
}

// pack two floats to two bf16 (RNE) in one dword; elem0 in low 16 bits
#if defined(__BF16_MANT_DIG__)
typedef __bf16 bfr2 __attribute__((ext_vector_type(2)));
__device__ __forceinline__ unsigned int pack_bf16(float a, float b) {
    union { bfr2 h; unsigned int u; } v;
    v.h = (bfr2){(__bf16)a, (__bf16)b};
    return v.u;
}
#else
__device__ __forceinline__ unsigned int pack_bf16(float a, float b) {
    return ((unsigned int)(unsigned short)f2bf(a)) |
           (((unsigned int)(unsigned short)f2bf(b)) << 16);
}
#endif

// load 8 consecutive fp32 and round to a bf16x8 MFMA fragment
__device__ __forceinline__ bf16x8 load8f(const float* __restrict__ p) {
    floatx4 a = *(const floatx4*)p;
    floatx4 b = *(const floatx4*)(p + 4);
    union { bf16x8 v; unsigned int u[4]; } r;
    r.u[0] = pack_bf16(a[0], a[1]);
    r.u[1] = pack_bf16(a[2], a[3]);
    r.u[2] = pack_bf16(b[0], b[1]);
    r.u[3] = pack_bf16(b[2], b[3]);
    return r.v;
}

// attention score -> exp weight (bit-identical across rounds)
__device__ __forceinline__ float score_exp(float ssv, float stv, float av) {
    float s = ssv + stv;
    s = fmaxf(s, 0.2f * s);            // leaky_relu(0.2)
    return EXP2((s + av) * LOG2E);
}

// ---------------------------------------------------------------------------
// Kernel 1: PT[b_rel][h][f][j] = sum_c x[b,j,c] * W_proj[f*H+h, c]  (bf16)
// PLUS s_src/s_tgt per (h, j) computed from the fp32 accumulators.
// ---------------------------------------------------------------------------
__global__ __launch_bounds__(256) void proj_kernel(
    const float* __restrict__ x,      // (BN, NN, FIN) fp32
    const float* __restrict__ wproj,  // (D, FIN) fp32
    const float* __restrict__ ssrc,   // (H, FO) fp32
    const float* __restrict__ stgt,   // (H, FO) fp32
    short* __restrict__ pt,           // (nb*D, NN) bf16 slabs
    float* __restrict__ sS,           // (nb*H, NN) fp32
    float* __restrict__ sT,           // (nb*H, NN) fp32
    int b0)
{
    const int tid  = threadIdx.x;
    const int wave = tid >> 6;
    const int lane = tid & 63;
    const int l16  = lane & 15;
    const int quad = lane >> 4;

    const int b_rel = blockIdx.z;
    const int b  = b0 + b_rel;
    const int h  = blockIdx.y;            // D_/64 == H_, so y-block == head
    const int d0 = h * 64;
    const int j0 = blockIdx.x * 256 + wave * 64;

    floatx4 acc[4][4];
#pragma unroll
    for (int mi = 0; mi < 4; ++mi)
#pragma unroll
        for (int nj = 0; nj < 4; ++nj)
            acc[mi][nj] = (floatx4){0.f, 0.f, 0.f, 0.f};

#pragma unroll
    for (int kc = 0; kc < 4; ++kc) {
        const int c = kc * 32 + quad * 8;
        bf16x8 afr[4], bfr[4];
#pragma unroll
        for (int mi = 0; mi < 4; ++mi) {
            int f = (d0 + mi * 16 + l16) & 63;
            int srow = f * H_ + h;                // W_proj row (flat d = f*H+h)
            afr[mi] = load8f(wproj + srow * FIN_ + c);
        }
#pragma unroll
        for (int nj = 0; nj < 4; ++nj) {
            int j = j0 + nj * 16 + l16;
            bfr[nj] = load8f(x + ((size_t)b * NN_ + j) * FIN_ + c);
        }
#pragma unroll
        for (int mi = 0; mi < 4; ++mi)
#pragma unroll
            for (int nj = 0; nj < 4; ++nj)
                acc[mi][nj] = __builtin_amdgcn_mfma_f32_16x16x32_bf16(
                    afr[mi], bfr[nj], acc[mi][nj], 0, 0, 0);
    }

    // C/D layout: col(n=j) = lane&15, row(m=f within head) = mi*16+quad*4+r
#pragma unroll
    for (int mi = 0; mi < 4; ++mi) {
#pragma unroll
        for (int r = 0; r < 4; ++r) {
            int dp = d0 + mi * 16 + quad * 4 + r;
            size_t base = ((size_t)b_rel * D_ + dp) * NN_;
#pragma unroll
            for (int nj = 0; nj < 4; ++nj) {
                int j = j0 + nj * 16 + l16;
                pt[base + j] = f2bf(acc[mi][nj][r]);
            }
        }
    }

    // ---- score dot-products from fp32 accumulators ----
    float wsv[4][4], wtv[4][4];
#pragma unroll
    for (int mi = 0; mi < 4; ++mi)
#pragma unroll
        for (int r = 0; r < 4; ++r) {
            int f = mi * 16 + quad * 4 + r;
            wsv[mi][r] = ssrc[h * FO_ + f];
            wtv[mi][r] = stgt[h * FO_ + f];
        }
    const size_t sbase = ((size_t)b_rel * H_ + h) * NN_;
#pragma unroll
    for (int nj = 0; nj < 4; ++nj) {
        float ps = 0.f, pg = 0.f;
#pragma unroll
        for (int mi = 0; mi < 4; ++mi)
#pragma unroll
            for (int r = 0; r < 4; ++r) {
                ps = fmaf(wsv[mi][r], acc[mi][nj][r], ps);
                pg = fmaf(wtv[mi][r], acc[mi][nj][r], pg);
            }
        ps += __shfl_xor(ps, 16, 64); ps += __shfl_xor(ps, 32, 64);
        pg += __shfl_xor(pg, 16, 64); pg += __shfl_xor(pg, 32, 64);
        if (quad == 0) {
            int j = j0 + nj * 16 + l16;
            sS[sbase + j] = ps;
            sT[sbase + j] = pg;
        }
    }
}

// ---------------------------------------------------------------------------
// Kernel 2: fused attention, 4 heads per block, i-tile = 16.
// Round-3/4: explicit register-level software pipeline. Round-2 counters
// (all pipes <26% busy, ~5K busy cycles vs 209K block residency, VGPR 84)
// indicated serial load-latency exposure: the compiler sinks the 18
// independent 16B loads per j-window next to their uses. PT fragments are
// prefetched one (jt, head-pair) stage ahead and adj one jt-window ahead
// into double-buffered registers; sched_barrier(0) pins issue above
// compute in each of the 16 fully-unrolled stages. All pipeline-buffer
// indices are compile-time constants (no scratch). ~210 VGPR < (512,2)'s
// 256 cap.
// ---------------------------------------------------------------------------
#define RSTRIDE 65   // LDS row stride (pad +1 col to break bank alignment)
#define WSLOT   (RSTRIDE * 16 + 16)   // 1056 floats per wave slot

__global__ __launch_bounds__(512, 2) void attn_kernel(
    const float* __restrict__ adj,    // (BN, NN, NN) fp32
    const short* __restrict__ pt,     // (nb*D, NN) bf16
    const float* __restrict__ sS,     // (nb*H, NN) fp32
    const float* __restrict__ sT,     // (nb*H, NN) fp32
    const float* __restrict__ bias,   // (D,) fp32
    float* __restrict__ out,          // (BN, NN, D) fp32
    int b0)
{
    // st (main loop) and red (epilogue) never live simultaneously; the
    // h=0 epilogue __syncthreads separates all st reads from red writes.
    __shared__ union {
        float st[8][4][256];          // per-wave s_tgt slices, 4 heads (32 KiB)
        float red[8][WSLOT];          // cross-wave reduction scratch (33 KiB)
    } sm;

    const int tid  = threadIdx.x;
    const int w    = tid >> 6;        // wave = 256-wide j-slice
    const int lane = tid & 63;
    const int l16  = lane & 15;
    const int quad = lane >> 4;

    const int b_rel = blockIdx.z;
    const int b  = b0 + b_rel;
    const int i0 = blockIdx.x * 16;

    const short* pt_b = pt + (size_t)b_rel * D_ * NN_;
    const size_t sb = (size_t)b_rel * H_ * NN_;

    // stage s_tgt slices for all 4 heads (wave-private; no barrier needed)
    {
        const int t = lane * 4;
#pragma unroll
        for (int h = 0; h < 4; ++h)
            *(floatx4*)&sm.st[w][h][t] =
                *(const floatx4*)&sT[sb + (size_t)h * NN_ + w * 256 + t];
    }

    // per-lane s_src for my i-row (row = l16), all heads
    float ssv[4];
#pragma unroll
    for (int h = 0; h < 4; ++h)
        ssv[h] = sS[sb + (size_t)h * NN_ + i0 + l16];

    // pre-offset global bases (j-slice + quad offset folded in)
    const int qo = quad * 8;
    const float* adj_p = adj + ((size_t)b * NN_ + i0 + l16) * NN_ + w * 256 + qo;
    const short* ptr_hk[4][4];
#pragma unroll
    for (int h = 0; h < 4; ++h)
#pragma unroll
        for (int K = 0; K < 4; ++K)
            ptr_hk[h][K] = pt_b + (size_t)(h * FO_ + K * 16 + l16) * NN_ + w * 256 + qo;

    floatx4 acc[4][4];                // [head][f-block], 64 regs
#pragma unroll
    for (int h = 0; h < 4; ++h)
#pragma unroll
        for (int K = 0; K < 4; ++K)
            acc[h][K] = (floatx4){0.f, 0.f, 0.f, 0.f};
    float ls[4] = {0.f, 0.f, 0.f, 0.f};

    // ---- software pipeline: 16 stages = 8 jt-windows x 2 head-pairs ----
    bf16x8 ptb[2][2][4];              // [stage parity][head-in-pair][K]
    floatx4 ajb[2][2];                // [jt parity][lo/hi half]

    // prologue: adj window 0 + PT for stage 0 (heads 0,1 @ jt0)
    ajb[0][0] = *(const floatx4*)(adj_p);
    ajb[0][1] = *(const floatx4*)(adj_p + 4);
#pragma unroll
    for (int K = 0; K < 4; ++K) {
        ptb[0][0][K] = *(const bf16x8*)(ptr_hk[0][K]);
        ptb[0][1][K] = *(const bf16x8*)(ptr_hk[1][K]);
    }

#pragma unroll
    for (int s = 0; s < 16; ++s) {
        const int jt = s >> 1, hp = s & 1;
        const int o  = jt * 32;       // static element offset in j-slice

        // ---- issue next-stage loads (before compute; pinned below) ----
        if (hp == 0 && jt < 7) {      // adj for jt+1, one window ahead
            ajb[(jt + 1) & 1][0] = *(const floatx4*)(adj_p + o + 32);
            ajb[(jt + 1) & 1][1] = *(const floatx4*)(adj_p + o + 36);
        }
        if (s < 15) {                 // PT fragments for stage s+1
            const int ns = s + 1, njt = ns >> 1, nhp = ns & 1;
            const int no = njt * 32;
#pragma unroll
            for (int K = 0; K < 4; ++K) {
                ptb[ns & 1][0][K] = *(const bf16x8*)(ptr_hk[nhp * 2 + 0][K] + no);
                ptb[ns & 1][1][K] = *(const bf16x8*)(ptr_hk[nhp * 2 + 1][K] + no);
            }
        }
        __builtin_amdgcn_sched_barrier(0);   // keep issue above compute

        // ---- compute stage s: heads {2*hp, 2*hp+1} of window jt ----
        floatx4 ajA = ajb[jt & 1][0];
        floatx4 ajB = ajb[jt & 1][1];
#pragma unroll
        for (int u = 0; u < 2; ++u) {
            const int hh = hp * 2 + u;
            const float* stp = &sm.st[w][hh][qo];
            floatx4 stA = *(const floatx4*)(stp + o);
            floatx4 stB = *(const floatx4*)(stp + o + 4);

            float w0 = score_exp(ssv[hh], stA[0], ajA[0]);
            float w1 = score_exp(ssv[hh], stA[1], ajA[1]);
            float w2 = score_exp(ssv[hh], stA[2], ajA[2]);
            float w3 = score_exp(ssv[hh], stA[3], ajA[3]);
            float w4 = score_exp(ssv[hh], stB[0], ajB[0]);
            float w5 = score_exp(ssv[hh], stB[1], ajB[1]);
            float w6 = score_exp(ssv[hh], stB[2], ajB[2]);
            float w7 = score_exp(ssv[hh], stB[3], ajB[3]);
            ls[hh] += ((w0 + w1) + (w2 + w3)) + ((w4 + w5) + (w6 + w7));
            union { bf16x8 v; unsigned int u4[4]; } a0;
            a0.u4[0] = pack_bf16(w0, w1);
            a0.u4[1] = pack_bf16(w2, w3);
            a0.u4[2] = pack_bf16(w4, w5);
            a0.u4[3] = pack_bf16(w6, w7);
#pragma unroll
            for (int K = 0; K < 4; ++K)
                acc[hh][K] = __builtin_amdgcn_mfma_f32_16x16x32_bf16(
                    a0.v, ptb[s & 1][u][K], acc[hh][K], 0, 0, 0);
        }
    }

    // wave-local row-sums over quads (row = l16 in A-layout)
#pragma unroll
    for (int h = 0; h < 4; ++h) {
        ls[h] += __shfl_xor(ls[h], 16, 64);
        ls[h] += __shfl_xor(ls[h], 32, 64);
    }

    // epilogue: 4 head-chunks of 16 rows; 8-wave LDS reduction per chunk
#pragma unroll
    for (int h = 0; h < 4; ++h) {
        __syncthreads();   // h=0: all st reads done; h>0: prev chunk read done
#pragma unroll
        for (int K = 0; K < 4; ++K)
#pragma unroll
            for (int r = 0; r < 4; ++r)
                sm.red[w][(quad * 4 + r) * RSTRIDE + K * 16 + l16] = acc[h][K][r];
        if (quad == 0)
            sm.red[w][16 * RSTRIDE + l16] = ls[h];
        __syncthreads();
#pragma unroll
        for (int p = 0; p < 2; ++p) {
            int e   = tid + p * 512;
            int row = e >> 6;
            int col = e & 63;
            float s = 0.f, l = 0.f;
#pragma unroll
            for (int ww = 0; ww < 8; ++ww) {
                s += sm.red[ww][row * RSTRIDE + col];
                l += sm.red[ww][16 * RSTRIDE + row];
            }
            float v = s / l + bias[h * FO_ + col];
            v = (v > 0.f) ? v : expm1f(v);        // elu (fp32 out)
            out[((size_t)b * NN_ + i0 + row) * D_ + h * FO_ + col] = v;
        }
    }
}

// ---------------------------------------------------------------------------
extern "C" void kernel_launch(void* const* d_in, const int* in_sizes, int n_in,
                              void* d_out, int out_size, void* d_ws, size_t ws_size,
                              hipStream_t stream) {
    const float* x     = (const float*)d_in[0];   // (4,2048,128) fp32
    const float* adj   = (const float*)d_in[1];   // (4,2048,2048) fp32
    const float* wproj = (const float*)d_in[2];   // (256,128) fp32
    const float* ssrc  = (const float*)d_in[3];   // (4,64) fp32
    const float* stgt  = (const float*)d_in[4];   // (4,64) fp32
    const float* bias  = (const float*)d_in[5];   // (256,) fp32
    float* out = (float*)d_out;                   // (4,2048,256) fp32

    // ws layout per batch: PT slab (1 MiB) + s_src/s_tgt (64 KiB)
    const size_t SLAB  = (size_t)D_ * NN_ * 2;          // bf16 PT
    const size_t SSLAB = (size_t)2 * H_ * NN_ * 4;      // fp32 sS+sT
    int nb = (int)(ws_size / (SLAB + SSLAB));
    if (nb < 1) nb = 1;
    if (nb > 4) nb = 4;

    short* pt = (short*)d_ws;
    float* sv = (float*)((char*)d_ws + (size_t)nb * SLAB);
    float* sS = sv;
    float* sT = sv + (size_t)nb * H_ * NN_;

    for (int bb0 = 0; bb0 < BN_; bb0 += nb) {
        int cnt = (BN_ - bb0 < nb) ? (BN_ - bb0) : nb;
        proj_kernel<<<dim3(NN_ / 256, H_, cnt), 256, 0, stream>>>(
            x, wproj, ssrc, stgt, pt, sS, sT, bb0);
        attn_kernel<<<dim3(NN_ / 16, 1, cnt), 512, 0, stream>>>(
            adj, pt, sS, sT, bias, out, bb0);
    }
}